// Round 1
// baseline (115.935 us; speedup 1.0000x reference)
//
#include <hip/hip_runtime.h>

// Chamfer loss: pred (2048,8,3) vs gt (2048,8,3) fp32. N=16384 pts/side.
// out = mean(min_m d) + mean(min_n d); 8-corner group-mean == global mean.
//
// R4 (fused single-kernel):
//  - hipMemsetAsync(0x7F) initializes both the 2*N min slots (0x7F7F7F7F =
//    3.39e38f > any d2) and the ticket counter -> init_mins kernel removed.
//  - last-block ticket (atomicSub) folds the sqrt+sum reduction into the
//    main kernel -> chamfer_reduce kernel removed. 3 launches -> memset+1.
//  - occupancy: RPT 16->4, NSEG 128->64 => grid (16,64,2)=2048 blocks
//    = 8 blocks/CU = 32 waves/CU (was 4 blocks/CU, 26% occupancy, 62%
//    VALUBusy). Halves atomicMin traffic too (2*N*NSEG = 2.1M).
//  - y processed in pairs; min-merge via v_max3_f32 (fmaxf(fmaxf(a,b),c)
//    fusion): per 4 pairs 6 pk_fma + 2 max3 = 7 cyc/pair vs 8 with pk_max
//    (v_pk_* is 4 cyc on gfx950 SIMD-32 - packing saves issue slots, not
//    FLOP cycles; fp32 peak 157.3 TF assumes plain 2-cyc wave64 FMA).

#define NPTS   16384
#define RPT    4              // x-points per thread (2 packed lanes)
#define RPT2   (RPT / 2)
#define BLOCK  256
#define XPB    (RPT * BLOCK)  // 1024 x-points per block
#define NXB    (NPTS / XPB)   // 16 x-blocks
#define NSEG   64             // y segments -> 16*64*2 = 2048 blocks (8/CU)
#define YSEG   (NPTS / NSEG)  // 256 y-points per segment (one LDS chunk)
#define GRID   (NXB * NSEG * 2)
#define TICKET0 0x7F7F7F7Fu   // memset(0x7F) pattern = ticket initial value

typedef float v2f __attribute__((ext_vector_type(2)));

__global__ __launch_bounds__(BLOCK, 8) void chamfer_fused(
        const float* __restrict__ pred, const float* __restrict__ gt,
        unsigned int* __restrict__ mins, float* __restrict__ out) {
    const int xb  = blockIdx.x;
    const int ys  = blockIdx.y;
    const int dir = blockIdx.z;
    const float* __restrict__ X = dir ? gt : pred;
    const float* __restrict__ Y = dir ? pred : gt;
    unsigned int* __restrict__ outm   = mins + dir * NPTS;
    unsigned int* __restrict__ ticket = mins + 2 * NPTS;
    const int tid = threadIdx.x;

    __shared__ float4 sh[YSEG];  // (yx, yy, yz, -|y|^2/2)
    __shared__ float  wsum[BLOCK / 64];
    __shared__ int    lastflag;

    {   // YSEG == BLOCK: every thread stages one y-point
        int yi = ys * YSEG + tid;
        float a = Y[3 * yi + 0], b = Y[3 * yi + 1], c = Y[3 * yi + 2];
        sh[tid] = make_float4(a, b, c, -0.5f * (a * a + b * b + c * c));
    }

    // x-points in registers, packed 2-wide (pair r=2k, 2k+1)
    v2f xx[RPT2], xy[RPT2], xz[RPT2], x2[RPT2], mx[RPT2];
    const int xbase = xb * XPB;
#pragma unroll
    for (int k = 0; k < RPT2; ++k) {
        int i0 = xbase + (2 * k + 0) * BLOCK + tid;
        int i1 = xbase + (2 * k + 1) * BLOCK + tid;
        xx[k] = (v2f){X[3 * i0 + 0], X[3 * i1 + 0]};
        xy[k] = (v2f){X[3 * i0 + 1], X[3 * i1 + 1]};
        xz[k] = (v2f){X[3 * i0 + 2], X[3 * i1 + 2]};
        x2[k] = xx[k] * xx[k] + xy[k] * xy[k] + xz[k] * xz[k];
        mx[k] = (v2f){-3.0e38f, -3.0e38f};
    }

    __syncthreads();

    // t = x.y - |y|^2/2 ; min d2 = |x|^2 - 2*max t. Two y per step so the
    // running-max merge is one scalar v_max3_f32 per packed component.
#pragma unroll 2
    for (int j = 0; j < YSEG; j += 2) {
        float4 y0 = sh[j + 0];  // uniform address -> broadcast, conflict-free
        float4 y1 = sh[j + 1];
        v2f y0x = {y0.x, y0.x}, y0y = {y0.y, y0.y}, y0z = {y0.z, y0.z}, y0w = {y0.w, y0.w};
        v2f y1x = {y1.x, y1.x}, y1y = {y1.y, y1.y}, y1z = {y1.z, y1.z}, y1w = {y1.w, y1.w};
#pragma unroll
        for (int k = 0; k < RPT2; ++k) {
            v2f ta = __builtin_elementwise_fma(xz[k], y0z, y0w);  // v_pk_fma_f32
            ta = __builtin_elementwise_fma(xy[k], y0y, ta);
            ta = __builtin_elementwise_fma(xx[k], y0x, ta);
            v2f tb = __builtin_elementwise_fma(xz[k], y1z, y1w);
            tb = __builtin_elementwise_fma(xy[k], y1y, tb);
            tb = __builtin_elementwise_fma(xx[k], y1x, tb);
            mx[k].x = fmaxf(fmaxf(ta.x, tb.x), mx[k].x);  // v_max3_f32
            mx[k].y = fmaxf(fmaxf(ta.y, tb.y), mx[k].y);
        }
    }

#pragma unroll
    for (int k = 0; k < RPT2; ++k) {
        v2f d2 = __builtin_elementwise_max(
            __builtin_elementwise_fma((v2f){-2.0f, -2.0f}, mx[k], x2[k]),
            (v2f){0.0f, 0.0f});
        int i0 = xbase + (2 * k + 0) * BLOCK + tid;
        int i1 = xbase + (2 * k + 1) * BLOCK + tid;
        atomicMin(&outm[i0], __float_as_uint(d2.x));
        atomicMin(&outm[i1], __float_as_uint(d2.y));
    }

    // --- last-block reduction ---------------------------------------------
    // __syncthreads lowers to s_waitcnt vmcnt(0)+barrier per wave: all this
    // block's atomicMins are complete (device-scope) before the ticket.
    __syncthreads();
    if (tid == 0) {
        __threadfence();
        unsigned int old = atomicSub(ticket, 1u);
        lastflag = (old == TICKET0 - (GRID - 1));
    }
    __syncthreads();
    if (!lastflag) return;

    __threadfence();  // acquire side of the ticket chain
    float s = 0.0f;
#pragma unroll 4
    for (int i = tid; i < 2 * NPTS; i += BLOCK) {
        // agent-scope load: coherent with other XCDs' atomicMin results
        unsigned int m = __hip_atomic_load(&mins[i], __ATOMIC_RELAXED,
                                           __HIP_MEMORY_SCOPE_AGENT);
        s += sqrtf(__uint_as_float(m));
    }
#pragma unroll
    for (int off = 32; off > 0; off >>= 1)
        s += __shfl_down(s, off, 64);
    if ((tid & 63) == 0) wsum[tid >> 6] = s;
    __syncthreads();
    if (tid == 0)
        out[0] = (wsum[0] + wsum[1] + wsum[2] + wsum[3]) * (1.0f / (float)NPTS);
}

extern "C" void kernel_launch(void* const* d_in, const int* in_sizes, int n_in,
                              void* d_out, int out_size, void* d_ws, size_t ws_size,
                              hipStream_t stream) {
    const float* pred = (const float*)d_in[0];
    const float* gt   = (const float*)d_in[1];
    float* out        = (float*)d_out;
    unsigned int* mins = (unsigned int*)d_ws;  // 2*NPTS uints + 1 ticket uint

    // 0x7F7F7F7F = 3.39e38f (> any d2) for the min slots AND the ticket start
    hipMemsetAsync(d_ws, 0x7F, (2 * NPTS + 1) * sizeof(unsigned int), stream);
    hipLaunchKernelGGL(chamfer_fused, dim3(NXB, NSEG, 2), dim3(BLOCK), 0, stream,
                       pred, gt, mins, out);
}